// Round 1
// baseline (66.258 us; speedup 1.0000x reference)
//
#include <hip/hip_runtime.h>
#include <math.h>

#define NB 32          // batch
#define NM 32          // max GT per image
#define NA 3           // anchors per scale
#define NCLS 80
#define NCH 85         // 5 + C
#define IOU_THR 0.7f
#define L_COORD 0.75f
#define FEPS 1e-8f

__device__ __forceinline__ float sigmoidf_(float x) {
    return 1.0f / (1.0f + expf(-x));
}

// ---------------------------------------------------------------------------
// Prep: per-(b,m) GT entry -> workspace, 12 floats each:
// 0 x1, 1 y1, 2 x2, 3 y2, 4 area, 5 cx, 6 cy, 7 weight, 8 tw, 9 th, 10 bp
// Also zeroes the output scalar.
// ---------------------------------------------------------------------------
__global__ void yolo_prep(const float* __restrict__ gt_boxes,
                          const float* __restrict__ anchors,
                          float* __restrict__ W,
                          float* __restrict__ out) {
    int i = blockIdx.x * blockDim.x + threadIdx.x;
    if (i == 0) out[0] = 0.0f;
    if (i >= NB * NM) return;

    float cx = gt_boxes[i * 4 + 0];
    float cy = gt_boxes[i * 4 + 1];
    float w  = gt_boxes[i * 4 + 2];
    float h  = gt_boxes[i * 4 + 3];

    // best prior: argmax over 9 anchors of min-intersection IoU (first-max tie)
    float best = -1.0f;
    int bp = 0;
    float area_g = w * h;
    for (int k = 0; k < 9; ++k) {
        float aw = anchors[k * 2 + 0];
        float ah = anchors[k * 2 + 1];
        float inter = fminf(w, aw) * fminf(h, ah);
        float uni = area_g + aw * ah - inter;
        float r = inter / (uni + FEPS);
        if (r > best) { best = r; bp = k; }
    }

    float x1 = cx - w * 0.5f, y1 = cy - h * 0.5f;
    float x2 = cx + w * 0.5f, y2 = cy + h * 0.5f;

    float* e = W + (size_t)i * 12;
    e[0] = x1; e[1] = y1; e[2] = x2; e[3] = y2;
    e[4] = (x2 - x1) * (y2 - y1);
    e[5] = cx; e[6] = cy;
    e[7] = 2.0f - area_g;                                    // weight
    e[8] = logf(fmaxf(w, FEPS)) - logf(anchors[bp * 2 + 0]); // tw target
    e[9] = logf(fmaxf(h, FEPS)) - logf(anchors[bp * 2 + 1]); // th target
    e[10] = (float)bp;
    e[11] = 0.0f;
}

// ---------------------------------------------------------------------------
// noobj: for every (b, a, cell) of scale S: decode box, positivity test vs
// 32 GT (IoU>0.7 OR matched-cell), accumulate sig(obj)^2 when negative.
// ---------------------------------------------------------------------------
template <int G, int S>
__global__ void yolo_noobj(const float* __restrict__ p,
                           const float* __restrict__ anchors,
                           const float* __restrict__ W,
                           float* __restrict__ out) {
    constexpr int GG = G * G;
    constexpr int CHUNKS = (GG + 255) / 256;

    int bid = blockIdx.x;
    int chunk = bid % CHUNKS;
    int a = (bid / CHUNKS) % NA;
    int b = bid / (CHUNKS * NA);
    int tid = threadIdx.x;

    __shared__ float sx1[NM], sy1[NM], sx2[NM], sy2[NM], sarea[NM];
    __shared__ int scode[NM];

    if (tid < NM) {
        const float* e = W + (size_t)(b * NM + tid) * 12;
        sx1[tid] = e[0]; sy1[tid] = e[1];
        sx2[tid] = e[2]; sy2[tid] = e[3];
        sarea[tid] = e[4];
        int bp = (int)e[10];
        int code = -1;
        if (bp >= S * NA && bp < S * NA + NA) {
            float cx = e[5], cy = e[6];
            float gxf = fminf(fmaxf(floorf(cx * (float)G), 0.0f), (float)(G - 1));
            float gyf = fminf(fmaxf(floorf(cy * (float)G), 0.0f), (float)(G - 1));
            code = (bp - S * NA) * GG + (int)gyf * G + (int)gxf;
        }
        scode[tid] = code;
    }
    __syncthreads();

    float aw = anchors[(S * NA + a) * 2 + 0];
    float ah = anchors[(S * NA + a) * 2 + 1];

    int pix = chunk * 256 + tid;
    float local = 0.0f;
    if (pix < GG) {
        int gy = pix / G, gx = pix % G;
        const float* base = p + (size_t)(b * (NA * NCH) + a * NCH) * GG + pix;
        float tx = base[0 * GG];
        float ty = base[1 * (size_t)GG];
        float tw = base[2 * (size_t)GG];
        float th = base[3 * (size_t)GG];
        float to = base[4 * (size_t)GG];

        float stx = sigmoidf_(tx), sty = sigmoidf_(ty);
        float bcx = (stx + (float)gx) / (float)G;
        float bcy = (sty + (float)gy) / (float)G;
        float bw = aw * expf(tw);
        float bh = ah * expf(th);
        float bx1 = bcx - bw * 0.5f, by1 = bcy - bh * 0.5f;
        float bx2 = bcx + bw * 0.5f, by2 = bcy + bh * 0.5f;
        float areab = (bx2 - bx1) * (by2 - by1);

        int mycode = a * GG + pix;
        bool pos = false;
        #pragma unroll 8
        for (int m = 0; m < NM; ++m) {
            float ltx = fmaxf(sx1[m], bx1), lty = fmaxf(sy1[m], by1);
            float rbx = fminf(sx2[m], bx2), rby = fminf(sy2[m], by2);
            float wx = fmaxf(rbx - ltx, 0.0f), wy = fmaxf(rby - lty, 0.0f);
            float inter = wx * wy;
            float denom = sarea[m] + areab - inter + FEPS;
            pos = pos || (inter > IOU_THR * denom);  // iou > THR (denom > 0)
            pos = pos || (scode[m] == mycode);       // positivity set to 1.0
        }
        if (!pos) {
            float so = sigmoidf_(to);
            local = so * so;
        }
    }

    // block reduce: wave shuffle -> LDS -> atomicAdd
    for (int off = 32; off; off >>= 1) local += __shfl_down(local, off);
    __shared__ float wsum[4];
    if ((tid & 63) == 0) wsum[tid >> 6] = local;
    __syncthreads();
    if (tid == 0) {
        float s = wsum[0] + wsum[1] + wsum[2] + wsum[3];
        if (s != 0.0f) atomicAdd(out, s);
    }
}

// ---------------------------------------------------------------------------
// Matched losses: one block (128 threads) per (b,m) entry of scale S.
// Gather 85 channels at the matched cell, compute coord/obj/cls terms.
// ---------------------------------------------------------------------------
template <int G, int S, int NBOFF>
__global__ void yolo_matched(const float* __restrict__ p,
                             const float* __restrict__ W,
                             const int* __restrict__ gt_classes,
                             float* __restrict__ out) {
    constexpr int GG = G * G;
    int e = blockIdx.x;          // 0 .. B*M-1
    int b = e / NM;

    const float* E = W + (size_t)e * 12;
    int bp = (int)E[10];
    int a = bp - S * NA;
    if (a < 0 || a >= NA) return;            // mask_s false: uniform exit

    float cx = E[5], cy = E[6];
    float gxf = fminf(fmaxf(floorf(cx * (float)G), 0.0f), (float)(G - 1));
    float gyf = fminf(fmaxf(floorf(cy * (float)G), 0.0f), (float)(G - 1));
    int gx = (int)gxf, gy = (int)gyf;
    int box_idx = a * GG + gy * G + gx;
    long gidx = (long)NBOFF + (long)b * (NA * GG) + box_idx;
    if (gidx == 0) return;                   // valid = mask & (gidx != 0)

    float dx = cx * (float)G - gxf;
    float dy = cy * (float)G - gyf;
    float wgt = E[7], twt = E[8], tht = E[9];
    int cls = gt_classes[e];

    int tid = threadIdx.x;
    float term = 0.0f;
    if (tid < NCH) {
        float val = p[(size_t)(b * (NA * NCH) + a * NCH + tid) * GG + gy * G + gx];
        if (tid < 2) {
            float sv = sigmoidf_(val);
            float d = sv - (tid == 0 ? dx : dy);
            term = L_COORD * wgt * d * d;
        } else if (tid < 4) {
            float d = val - (tid == 2 ? twt : tht);
            term = L_COORD * wgt * d * d;
        } else if (tid == 4) {
            float sv = sigmoidf_(val);
            term = (sv - 1.0f) * (sv - 1.0f);
        } else {
            float sv = sigmoidf_(val);
            float oh = ((tid - 5) == cls) ? 1.0f : 0.0f;
            term = (sv - oh) * (sv - oh);
        }
    }

    for (int off = 32; off; off >>= 1) term += __shfl_down(term, off);
    __shared__ float wsum[2];
    if ((tid & 63) == 0) wsum[tid >> 6] = term;
    __syncthreads();
    if (tid == 0) atomicAdd(out, wsum[0] + wsum[1]);
}

// ---------------------------------------------------------------------------
extern "C" void kernel_launch(void* const* d_in, const int* in_sizes, int n_in,
                              void* d_out, int out_size, void* d_ws, size_t ws_size,
                              hipStream_t stream) {
    const float* p0 = (const float*)d_in[0];
    const float* p1 = (const float*)d_in[1];
    const float* p2 = (const float*)d_in[2];
    const float* gt_boxes = (const float*)d_in[3];
    const int* gt_classes = (const int*)d_in[4];
    const float* anchors = (const float*)d_in[5];
    float* out = (float*)d_out;
    float* W = (float*)d_ws;   // 1024 * 12 floats = 48 KB

    // prep (also zeroes out[0]); later kernels on same stream see the zero.
    yolo_prep<<<4, 256, 0, stream>>>(gt_boxes, anchors, W, out);

    // noobj per scale: grid = B * A * ceil(G*G/256)
    yolo_noobj<13, 0><<<32 * 3 * 1, 256, 0, stream>>>(p0, anchors, W, out);
    yolo_noobj<26, 1><<<32 * 3 * 3, 256, 0, stream>>>(p1, anchors, W, out);
    yolo_noobj<52, 2><<<32 * 3 * 11, 256, 0, stream>>>(p2, anchors, W, out);

    // matched losses: 1024 entries per scale
    // nb_off: s0=0, s1=32*3*169=16224, s2=16224+32*3*676=81120
    yolo_matched<13, 0, 0>     <<<1024, 128, 0, stream>>>(p0, W, gt_classes, out);
    yolo_matched<26, 1, 16224> <<<1024, 128, 0, stream>>>(p1, W, gt_classes, out);
    yolo_matched<52, 2, 81120> <<<1024, 128, 0, stream>>>(p2, W, gt_classes, out);
}

// Round 2
// 47.455 us; speedup vs baseline: 1.3962x; 1.3962x over previous
//
#include <hip/hip_runtime.h>
#include <math.h>

#define NB 32          // batch
#define NM 32          // max GT per image
#define NA 3           // anchors per scale
#define NCLS 80
#define NCH 85         // 5 + C
#define IOU_THR 0.7f
#define L_COORD 0.75f
#define FEPS 1e-8f

// grid layout for the fused kernel
#define NOOBJ0_BLOCKS (NB * NA * 1)    // G=13: 169 -> 1 chunk of 256
#define NOOBJ1_BLOCKS (NB * NA * 3)    // G=26: 676 -> 3 chunks
#define NOOBJ2_BLOCKS (NB * NA * 11)   // G=52: 2704 -> 11 chunks
#define OFF1 (NOOBJ0_BLOCKS)
#define OFF2 (OFF1 + NOOBJ1_BLOCKS)
#define OFFM (OFF2 + NOOBJ2_BLOCKS)               // 1440
#define MATCHED_BLOCKS (3 * NB * NM / 4)          // 3072 wave-tasks / 4 waves = 768
#define TOTAL_BLOCKS (OFFM + MATCHED_BLOCKS)      // 2208

struct Smem {
    float sx1[NM], sy1[NM], sx2[NM], sy2[NM], sarea[NM];
    int   scode[NM];
    float wsum[4];
};

__device__ __forceinline__ float sigmoidf_(float x) {
    return 1.0f / (1.0f + expf(-x));
}

// argmax over 9 anchors of min-intersection IoU (first-max tie, like jnp.argmax)
__device__ __forceinline__ int best_prior(const float* __restrict__ anchors,
                                          float w, float h, float area_g) {
    float best = -1.0f;
    int bp = 0;
    #pragma unroll
    for (int k = 0; k < 9; ++k) {
        float aw = anchors[k * 2 + 0];
        float ah = anchors[k * 2 + 1];
        float inter = fminf(w, aw) * fminf(h, ah);
        float uni = area_g + aw * ah - inter;
        float r = inter / (uni + FEPS);
        if (r > best) { best = r; bp = k; }
    }
    return bp;
}

// ---------------------------------------------------------------------------
// noobj body: one block = (b, a, chunk) of scale S. Recomputes the 32 GT
// entries of batch b inline (no prep pass), then per-cell positivity test.
// ---------------------------------------------------------------------------
template <int G, int S>
__device__ void noobj_body(const float* __restrict__ p,
                           const float* __restrict__ gt_boxes,
                           const float* __restrict__ anchors,
                           float* __restrict__ out, int bid, Smem& sm) {
    constexpr int GG = G * G;
    constexpr int CHUNKS = (GG + 255) / 256;

    int chunk = bid % CHUNKS;
    int a = (bid / CHUNKS) % NA;
    int b = bid / (CHUNKS * NA);
    int tid = threadIdx.x;

    if (tid < NM) {
        int e = b * NM + tid;
        float cx = gt_boxes[e * 4 + 0];
        float cy = gt_boxes[e * 4 + 1];
        float w  = gt_boxes[e * 4 + 2];
        float h  = gt_boxes[e * 4 + 3];
        float x1 = cx - w * 0.5f, y1 = cy - h * 0.5f;
        float x2 = cx + w * 0.5f, y2 = cy + h * 0.5f;
        sm.sx1[tid] = x1; sm.sy1[tid] = y1;
        sm.sx2[tid] = x2; sm.sy2[tid] = y2;
        sm.sarea[tid] = (x2 - x1) * (y2 - y1);
        int bp = best_prior(anchors, w, h, w * h);
        int code = -1;
        if (bp >= S * NA && bp < S * NA + NA) {
            float gxf = fminf(fmaxf(floorf(cx * (float)G), 0.0f), (float)(G - 1));
            float gyf = fminf(fmaxf(floorf(cy * (float)G), 0.0f), (float)(G - 1));
            code = (bp - S * NA) * GG + (int)gyf * G + (int)gxf;
        }
        sm.scode[tid] = code;
    }
    __syncthreads();

    float aw = anchors[(S * NA + a) * 2 + 0];
    float ah = anchors[(S * NA + a) * 2 + 1];

    int pix = chunk * 256 + tid;
    float local = 0.0f;
    if (pix < GG) {
        int gy = pix / G, gx = pix % G;
        const float* base = p + (size_t)(b * (NA * NCH) + a * NCH) * GG + pix;
        float tx = base[0];
        float ty = base[(size_t)GG];
        float tw = base[2 * (size_t)GG];
        float th = base[3 * (size_t)GG];
        float to = base[4 * (size_t)GG];

        float bcx = (sigmoidf_(tx) + (float)gx) / (float)G;
        float bcy = (sigmoidf_(ty) + (float)gy) / (float)G;
        float bw = aw * expf(tw);
        float bh = ah * expf(th);
        float bx1 = bcx - bw * 0.5f, by1 = bcy - bh * 0.5f;
        float bx2 = bcx + bw * 0.5f, by2 = bcy + bh * 0.5f;
        float areab = (bx2 - bx1) * (by2 - by1);

        int mycode = a * GG + pix;
        bool pos = false;
        #pragma unroll 8
        for (int m = 0; m < NM; ++m) {
            float ltx = fmaxf(sm.sx1[m], bx1), lty = fmaxf(sm.sy1[m], by1);
            float rbx = fminf(sm.sx2[m], bx2), rby = fminf(sm.sy2[m], by2);
            float wx = fmaxf(rbx - ltx, 0.0f), wy = fmaxf(rby - lty, 0.0f);
            float inter = wx * wy;
            float denom = sm.sarea[m] + areab - inter + FEPS;
            pos = pos || (inter > IOU_THR * denom);   // iou > THR (denom > 0)
            pos = pos || (sm.scode[m] == mycode);     // matched-cell override
        }
        if (!pos) {
            float so = sigmoidf_(to);
            local = so * so;
        }
    }

    // block reduce: wave shuffle -> LDS -> one atomic per block
    for (int off = 32; off; off >>= 1) local += __shfl_down(local, off);
    if ((tid & 63) == 0) sm.wsum[tid >> 6] = local;
    __syncthreads();
    if (tid == 0) {
        float s = sm.wsum[0] + sm.wsum[1] + sm.wsum[2] + sm.wsum[3];
        if (s != 0.0f) atomicAdd(out, s);
    }
}

// ---------------------------------------------------------------------------
// matched body: one wave per (scale, b, m) entry; 4 waves per block.
// Lane covers channels {lane, lane+64}. Entry data recomputed per-lane.
// ---------------------------------------------------------------------------
__device__ void matched_body(const float* __restrict__ p0,
                             const float* __restrict__ p1,
                             const float* __restrict__ p2,
                             const float* __restrict__ gt_boxes,
                             const int* __restrict__ gt_classes,
                             const float* __restrict__ anchors,
                             float* __restrict__ out, int mb) {
    int tid = threadIdx.x;
    int wave = tid >> 6, lane = tid & 63;
    int t = mb * 4 + wave;        // 0 .. 3071
    int s = t >> 10;              // scale: 1024 entries per scale
    int e = t & 1023;             // (b, m) flat
    int b = e >> 5;

    float cx = gt_boxes[e * 4 + 0];
    float cy = gt_boxes[e * 4 + 1];
    float w  = gt_boxes[e * 4 + 2];
    float h  = gt_boxes[e * 4 + 3];
    int bp = best_prior(anchors, w, h, w * h);
    int a = bp - s * NA;

    float term = 0.0f;
    if (a >= 0 && a < NA) {                       // mask_s (wave-uniform)
        const float* p = (s == 0) ? p0 : ((s == 1) ? p1 : p2);
        int G = (s == 0) ? 13 : ((s == 1) ? 26 : 52);
        long nboff = (s == 0) ? 0L : ((s == 1) ? 16224L : 81120L);
        int GG = G * G;

        float gxf = fminf(fmaxf(floorf(cx * (float)G), 0.0f), (float)(G - 1));
        float gyf = fminf(fmaxf(floorf(cy * (float)G), 0.0f), (float)(G - 1));
        int gx = (int)gxf, gy = (int)gyf;
        int box_idx = a * GG + gy * G + gx;
        long gidx = nboff + (long)b * (NA * GG) + box_idx;
        if (gidx != 0) {                          // valid (wave-uniform)
            float dx = cx * (float)G - gxf;
            float dy = cy * (float)G - gyf;
            float wgt = 2.0f - w * h;
            float twt = logf(fmaxf(w, FEPS)) - logf(anchors[bp * 2 + 0]);
            float tht = logf(fmaxf(h, FEPS)) - logf(anchors[bp * 2 + 1]);
            int cls = gt_classes[e];

            size_t cellbase = (size_t)(b * (NA * NCH) + a * NCH) * GG
                              + (size_t)(gy * G + gx);
            for (int ch = lane; ch < NCH; ch += 64) {
                float val = p[cellbase + (size_t)ch * GG];
                if (ch < 2) {
                    float sv = sigmoidf_(val);
                    float d = sv - (ch == 0 ? dx : dy);
                    term += L_COORD * wgt * d * d;
                } else if (ch < 4) {
                    float d = val - (ch == 2 ? twt : tht);
                    term += L_COORD * wgt * d * d;
                } else if (ch == 4) {
                    float sv = sigmoidf_(val);
                    term += (sv - 1.0f) * (sv - 1.0f);
                } else {
                    float sv = sigmoidf_(val);
                    float oh = ((ch - 5) == cls) ? 1.0f : 0.0f;
                    term += (sv - oh) * (sv - oh);
                }
            }
        }
    }

    // 64-lane wave reduce; one atomic per contributing wave
    for (int off = 32; off; off >>= 1) term += __shfl_down(term, off);
    if (lane == 0 && term != 0.0f) atomicAdd(out, term);
}

// ---------------------------------------------------------------------------
__global__ __launch_bounds__(256)
void yolo_fused(const float* __restrict__ p0,
                const float* __restrict__ p1,
                const float* __restrict__ p2,
                const float* __restrict__ gt_boxes,
                const int* __restrict__ gt_classes,
                const float* __restrict__ anchors,
                float* __restrict__ out) {
    __shared__ Smem sm;
    int bid = blockIdx.x;
    if (bid < OFF1) {
        noobj_body<13, 0>(p0, gt_boxes, anchors, out, bid, sm);
    } else if (bid < OFF2) {
        noobj_body<26, 1>(p1, gt_boxes, anchors, out, bid - OFF1, sm);
    } else if (bid < OFFM) {
        noobj_body<52, 2>(p2, gt_boxes, anchors, out, bid - OFF2, sm);
    } else {
        matched_body(p0, p1, p2, gt_boxes, gt_classes, anchors, out, bid - OFFM);
    }
}

// ---------------------------------------------------------------------------
extern "C" void kernel_launch(void* const* d_in, const int* in_sizes, int n_in,
                              void* d_out, int out_size, void* d_ws, size_t ws_size,
                              hipStream_t stream) {
    const float* p0 = (const float*)d_in[0];
    const float* p1 = (const float*)d_in[1];
    const float* p2 = (const float*)d_in[2];
    const float* gt_boxes = (const float*)d_in[3];
    const int* gt_classes = (const int*)d_in[4];
    const float* anchors = (const float*)d_in[5];
    float* out = (float*)d_out;

    hipMemsetAsync(out, 0, sizeof(float), stream);
    yolo_fused<<<TOTAL_BLOCKS, 256, 0, stream>>>(p0, p1, p2, gt_boxes,
                                                 gt_classes, anchors, out);
}

// Round 3
// 19.880 us; speedup vs baseline: 3.3329x; 2.3871x over previous
//
#include <hip/hip_runtime.h>
#include <math.h>

#define NB 32          // batch
#define NM 32          // max GT per image
#define NA 3           // anchors per scale
#define NCLS 80
#define NCH 85         // 5 + C
#define IOU_THR 0.7f
#define L_COORD 0.75f
#define FEPS 1e-8f

// grid layout for the fused kernel
#define NOOBJ0_BLOCKS (NB * NA * 1)    // G=13: 169 -> 1 chunk of 256
#define NOOBJ1_BLOCKS (NB * NA * 3)    // G=26: 676 -> 3 chunks
#define NOOBJ2_BLOCKS (NB * NA * 11)   // G=52: 2704 -> 11 chunks
#define OFF1 (NOOBJ0_BLOCKS)
#define OFF2 (OFF1 + NOOBJ1_BLOCKS)
#define OFFM (OFF2 + NOOBJ2_BLOCKS)               // 1440
#define MATCHED_BLOCKS (3 * NB * NM / 4)          // 3072 wave-tasks / 4 waves = 768
#define TOTAL_BLOCKS (OFFM + MATCHED_BLOCKS)      // 2208

struct Smem {
    float sx1[NM], sy1[NM], sx2[NM], sy2[NM], sarea[NM];
    int   scode[NM];
    float wsum[4];
};

__device__ __forceinline__ float sigmoidf_(float x) {
    return 1.0f / (1.0f + expf(-x));
}

// argmax over 9 anchors of min-intersection IoU (first-max tie, like jnp.argmax)
__device__ __forceinline__ int best_prior(const float* __restrict__ anchors,
                                          float w, float h, float area_g) {
    float best = -1.0f;
    int bp = 0;
    #pragma unroll
    for (int k = 0; k < 9; ++k) {
        float aw = anchors[k * 2 + 0];
        float ah = anchors[k * 2 + 1];
        float inter = fminf(w, aw) * fminf(h, ah);
        float uni = area_g + aw * ah - inter;
        float r = inter / (uni + FEPS);
        if (r > best) { best = r; bp = k; }
    }
    return bp;
}

// ---------------------------------------------------------------------------
// noobj body: one block = (b, a, chunk) of scale S. Recomputes the 32 GT
// entries of batch b inline, per-cell positivity test, returns block partial
// via sm.wsum (valid on tid 0 after the final __syncthreads-free read).
// ---------------------------------------------------------------------------
template <int G, int S>
__device__ float noobj_body(const float* __restrict__ p,
                            const float* __restrict__ gt_boxes,
                            const float* __restrict__ anchors,
                            int bid, Smem& sm) {
    constexpr int GG = G * G;
    constexpr int CHUNKS = (GG + 255) / 256;

    int chunk = bid % CHUNKS;
    int a = (bid / CHUNKS) % NA;
    int b = bid / (CHUNKS * NA);
    int tid = threadIdx.x;

    if (tid < NM) {
        int e = b * NM + tid;
        float cx = gt_boxes[e * 4 + 0];
        float cy = gt_boxes[e * 4 + 1];
        float w  = gt_boxes[e * 4 + 2];
        float h  = gt_boxes[e * 4 + 3];
        float x1 = cx - w * 0.5f, y1 = cy - h * 0.5f;
        float x2 = cx + w * 0.5f, y2 = cy + h * 0.5f;
        sm.sx1[tid] = x1; sm.sy1[tid] = y1;
        sm.sx2[tid] = x2; sm.sy2[tid] = y2;
        sm.sarea[tid] = (x2 - x1) * (y2 - y1);
        int bp = best_prior(anchors, w, h, w * h);
        int code = -1;
        if (bp >= S * NA && bp < S * NA + NA) {
            float gxf = fminf(fmaxf(floorf(cx * (float)G), 0.0f), (float)(G - 1));
            float gyf = fminf(fmaxf(floorf(cy * (float)G), 0.0f), (float)(G - 1));
            code = (bp - S * NA) * GG + (int)gyf * G + (int)gxf;
        }
        sm.scode[tid] = code;
    }
    __syncthreads();

    float aw = anchors[(S * NA + a) * 2 + 0];
    float ah = anchors[(S * NA + a) * 2 + 1];

    int pix = chunk * 256 + tid;
    float local = 0.0f;
    if (pix < GG) {
        int gy = pix / G, gx = pix % G;
        const float* base = p + (size_t)(b * (NA * NCH) + a * NCH) * GG + pix;
        float tx = base[0];
        float ty = base[(size_t)GG];
        float tw = base[2 * (size_t)GG];
        float th = base[3 * (size_t)GG];
        float to = base[4 * (size_t)GG];

        float bcx = (sigmoidf_(tx) + (float)gx) / (float)G;
        float bcy = (sigmoidf_(ty) + (float)gy) / (float)G;
        float bw = aw * expf(tw);
        float bh = ah * expf(th);
        float bx1 = bcx - bw * 0.5f, by1 = bcy - bh * 0.5f;
        float bx2 = bcx + bw * 0.5f, by2 = bcy + bh * 0.5f;
        float areab = (bx2 - bx1) * (by2 - by1);

        int mycode = a * GG + pix;
        bool pos = false;
        #pragma unroll 8
        for (int m = 0; m < NM; ++m) {
            float ltx = fmaxf(sm.sx1[m], bx1), lty = fmaxf(sm.sy1[m], by1);
            float rbx = fminf(sm.sx2[m], bx2), rby = fminf(sm.sy2[m], by2);
            float wx = fmaxf(rbx - ltx, 0.0f), wy = fmaxf(rby - lty, 0.0f);
            float inter = wx * wy;
            float denom = sm.sarea[m] + areab - inter + FEPS;
            pos = pos || (inter > IOU_THR * denom);   // iou > THR (denom > 0)
            pos = pos || (sm.scode[m] == mycode);     // matched-cell override
        }
        if (!pos) {
            float so = sigmoidf_(to);
            local = so * so;
        }
    }

    // block reduce: wave shuffle -> LDS
    for (int off = 32; off; off >>= 1) local += __shfl_down(local, off);
    if ((tid & 63) == 0) sm.wsum[tid >> 6] = local;
    __syncthreads();
    return sm.wsum[0] + sm.wsum[1] + sm.wsum[2] + sm.wsum[3];
}

// ---------------------------------------------------------------------------
// matched body: one wave per (scale, b, m) entry; 4 waves per block.
// Lane covers channels {lane, lane+64}. Returns block partial.
// ---------------------------------------------------------------------------
__device__ float matched_body(const float* __restrict__ p0,
                              const float* __restrict__ p1,
                              const float* __restrict__ p2,
                              const float* __restrict__ gt_boxes,
                              const int* __restrict__ gt_classes,
                              const float* __restrict__ anchors,
                              int mb, Smem& sm) {
    int tid = threadIdx.x;
    int wave = tid >> 6, lane = tid & 63;
    int t = mb * 4 + wave;        // 0 .. 3071
    int s = t >> 10;              // scale: 1024 entries per scale
    int e = t & 1023;             // (b, m) flat
    int b = e >> 5;

    float cx = gt_boxes[e * 4 + 0];
    float cy = gt_boxes[e * 4 + 1];
    float w  = gt_boxes[e * 4 + 2];
    float h  = gt_boxes[e * 4 + 3];
    int bp = best_prior(anchors, w, h, w * h);
    int a = bp - s * NA;

    float term = 0.0f;
    if (a >= 0 && a < NA) {                       // mask_s (wave-uniform)
        const float* p = (s == 0) ? p0 : ((s == 1) ? p1 : p2);
        int G = (s == 0) ? 13 : ((s == 1) ? 26 : 52);
        long nboff = (s == 0) ? 0L : ((s == 1) ? 16224L : 81120L);
        int GG = G * G;

        float gxf = fminf(fmaxf(floorf(cx * (float)G), 0.0f), (float)(G - 1));
        float gyf = fminf(fmaxf(floorf(cy * (float)G), 0.0f), (float)(G - 1));
        int gx = (int)gxf, gy = (int)gyf;
        int box_idx = a * GG + gy * G + gx;
        long gidx = nboff + (long)b * (NA * GG) + box_idx;
        if (gidx != 0) {                          // valid (wave-uniform)
            float dx = cx * (float)G - gxf;
            float dy = cy * (float)G - gyf;
            float wgt = 2.0f - w * h;
            float twt = logf(fmaxf(w, FEPS)) - logf(anchors[bp * 2 + 0]);
            float tht = logf(fmaxf(h, FEPS)) - logf(anchors[bp * 2 + 1]);
            int cls = gt_classes[e];

            size_t cellbase = (size_t)(b * (NA * NCH) + a * NCH) * GG
                              + (size_t)(gy * G + gx);
            for (int ch = lane; ch < NCH; ch += 64) {
                float val = p[cellbase + (size_t)ch * GG];
                if (ch < 2) {
                    float sv = sigmoidf_(val);
                    float d = sv - (ch == 0 ? dx : dy);
                    term += L_COORD * wgt * d * d;
                } else if (ch < 4) {
                    float d = val - (ch == 2 ? twt : tht);
                    term += L_COORD * wgt * d * d;
                } else if (ch == 4) {
                    float sv = sigmoidf_(val);
                    term += (sv - 1.0f) * (sv - 1.0f);
                } else {
                    float sv = sigmoidf_(val);
                    float oh = ((ch - 5) == cls) ? 1.0f : 0.0f;
                    term += (sv - oh) * (sv - oh);
                }
            }
        }
    }

    // 64-lane wave reduce -> LDS -> block partial
    for (int off = 32; off; off >>= 1) term += __shfl_down(term, off);
    if (lane == 0) sm.wsum[wave] = term;
    __syncthreads();
    return sm.wsum[0] + sm.wsum[1] + sm.wsum[2] + sm.wsum[3];
}

// ---------------------------------------------------------------------------
__global__ __launch_bounds__(256)
void yolo_fused(const float* __restrict__ p0,
                const float* __restrict__ p1,
                const float* __restrict__ p2,
                const float* __restrict__ gt_boxes,
                const int* __restrict__ gt_classes,
                const float* __restrict__ anchors,
                float* __restrict__ partials) {
    __shared__ Smem sm;
    int bid = blockIdx.x;
    float part;
    if (bid < OFF1) {
        part = noobj_body<13, 0>(p0, gt_boxes, anchors, bid, sm);
    } else if (bid < OFF2) {
        part = noobj_body<26, 1>(p1, gt_boxes, anchors, bid - OFF1, sm);
    } else if (bid < OFFM) {
        part = noobj_body<52, 2>(p2, gt_boxes, anchors, bid - OFF2, sm);
    } else {
        part = matched_body(p0, p1, p2, gt_boxes, gt_classes, anchors,
                            bid - OFFM, sm);
    }
    if (threadIdx.x == 0) partials[bid] = part;   // plain store, no init needed
}

// ---------------------------------------------------------------------------
// Final reduce: one block sums the 2208 partials, plain-stores out[0].
// ---------------------------------------------------------------------------
__global__ __launch_bounds__(256)
void yolo_reduce(const float* __restrict__ partials, float* __restrict__ out) {
    int tid = threadIdx.x;
    float s = 0.0f;
    for (int i = tid; i < TOTAL_BLOCKS; i += 256) s += partials[i];
    for (int off = 32; off; off >>= 1) s += __shfl_down(s, off);
    __shared__ float wsum[4];
    if ((tid & 63) == 0) wsum[tid >> 6] = s;
    __syncthreads();
    if (tid == 0) out[0] = wsum[0] + wsum[1] + wsum[2] + wsum[3];
}

// ---------------------------------------------------------------------------
extern "C" void kernel_launch(void* const* d_in, const int* in_sizes, int n_in,
                              void* d_out, int out_size, void* d_ws, size_t ws_size,
                              hipStream_t stream) {
    const float* p0 = (const float*)d_in[0];
    const float* p1 = (const float*)d_in[1];
    const float* p2 = (const float*)d_in[2];
    const float* gt_boxes = (const float*)d_in[3];
    const int* gt_classes = (const int*)d_in[4];
    const float* anchors = (const float*)d_in[5];
    float* out = (float*)d_out;
    float* partials = (float*)d_ws;   // TOTAL_BLOCKS floats, overwritten each call

    yolo_fused<<<TOTAL_BLOCKS, 256, 0, stream>>>(p0, p1, p2, gt_boxes,
                                                 gt_classes, anchors, partials);
    yolo_reduce<<<1, 256, 0, stream>>>(partials, out);
}